// Round 7
// baseline (1622.370 us; speedup 1.0000x reference)
//
#include <hip/hip_runtime.h>
#include <hip/hip_bf16.h>

// Problem dims (fixed)
#define BB 64      // batch
#define PP 196     // patches
#define ENCD 512   // encoder dim
#define ED 1024    // embed dim
#define HD 1024    // hidden
#define AD 512     // attention dim
#define VD 20000   // vocab
#define TT 24      // timesteps = lengths-1
#define VPAD 20096 // vocab padded to 128
#define HOFF 32768 // h-part offset (shorts) inside axh: 64 kc * 64 * 8

typedef __attribute__((ext_vector_type(8))) short short8;
typedef __attribute__((ext_vector_type(4))) short short4v;
typedef __attribute__((ext_vector_type(4))) float f32x4;

__device__ __forceinline__ float sigf(float x) { return 1.f / (1.f + __expf(-x)); }

// ---- fp32 -> bf16 split (hi + lo), RNE ----
__device__ __forceinline__ unsigned short f2bf(float f) {
    unsigned u = __builtin_bit_cast(unsigned, f);
    u = (u + 0x7FFFu + ((u >> 16) & 1u)) >> 16;
    return (unsigned short)u;
}
__device__ __forceinline__ void split2(float v, unsigned short& h, unsigned short& l) {
    h = f2bf(v);
    float hf = __builtin_bit_cast(float, ((unsigned)h) << 16);
    l = f2bf(v - hf);
}

// ---- weight split: fp32 [rows][N] -> chunked bf16 [K/8][Npad][8] hi/lo ----
// perm=1: output col n sources col (n&3)*1024 + (n>>2)  (gate-interleave)
__global__ __launch_bounds__(256) void split_w_kernel(
    const float* __restrict__ W, unsigned short* __restrict__ oh,
    unsigned short* __restrict__ ol, int N /*src pitch*/, int Npad, int coff,
    int Nlaunch, int rowoff, int perm) {
    int n = blockIdx.x * 256 + threadIdx.x;
    if (n >= Nlaunch) return;
    int kc = blockIdx.y;
    int src = perm ? ((n & 3) * 1024 + (n >> 2)) : n;
    short8 vh, vl;
    #pragma unroll
    for (int j = 0; j < 8; ++j) {
        float v = (src < N) ? W[(size_t)(rowoff + kc * 8 + j) * N + src] : 0.f;
        unsigned short h, l; split2(v, h, l);
        vh[j] = (short)h; vl[j] = (short)l;
    }
    size_t o = ((size_t)kc * Npad + coff + n) * 8;
    *(short8*)(oh + o) = vh; *(short8*)(ol + o) = vl;
}

// ---- embedding gather (fp32 rows, r = t*64+b) ----
__global__ __launch_bounds__(256) void embed_f32_kernel(
    const int* __restrict__ captions, const float* __restrict__ table,
    float* __restrict__ emb_f) {
    int t = blockIdx.x, b = blockIdx.y;
    int tok = captions[b * 25 + t];
    const float4* src = (const float4*)(table + (size_t)tok * ED);
    float4* dst = (float4*)(emb_f + ((size_t)t * BB + b) * ED);
    dst[threadIdx.x] = src[threadIdx.x];
}

// ---- permuted combined bias: out[n'] = b_ih[src]+b_hh[src] ----
__global__ __launch_bounds__(256) void bias_perm_kernel(
    const float* __restrict__ b_ih, const float* __restrict__ b_hh,
    float* __restrict__ out) {
    int n = blockIdx.x * 256 + threadIdx.x;
    int src = (n & 3) * 1024 + (n >> 2);
    out[n] = b_ih[src] + b_hh[src];
}

// ---- mean over patches ----
__global__ __launch_bounds__(512) void mean_kernel(const float* __restrict__ enc,
                                                   float* __restrict__ mf) {
    int b = blockIdx.x; int e = threadIdx.x;
    const float* base = enc + (size_t)b * PP * ENCD + e;
    float s = 0.f;
    #pragma unroll 4
    for (int p = 0; p < PP; ++p) s += base[(size_t)p * ENCD];
    mf[b * ENCD + e] = s * (1.f / PP);
}

// ---- h0/c0 init; h0 split written via hc pointers (pre-offset to axh h-part) ----
__global__ __launch_bounds__(256) void init_hc_kernel(
    const float* __restrict__ mf,
    const float* __restrict__ Wh, const float* __restrict__ bh,
    const float* __restrict__ Wc, const float* __restrict__ bc,
    unsigned short* __restrict__ hc_h, unsigned short* __restrict__ hc_l,
    float* __restrict__ c0) {
    int b = blockIdx.x;
    int isC = blockIdx.y;
    const float* W    = isC ? Wc : Wh;
    const float* bias = isC ? bc : bh;
    __shared__ float smf[ENCD];
    for (int i = threadIdx.x; i < ENCD; i += 256) smf[i] = mf[b * ENCD + i];
    __syncthreads();
    #pragma unroll
    for (int jj = 0; jj < 4; ++jj) {
        int j = threadIdx.x + jj * 256;
        float acc = bias[j];
        for (int k = 0; k < ENCD; ++k) acc += smf[k] * W[(size_t)k * HD + j];
        if (isC) c0[b * HD + j] = acc;
        else {
            unsigned short h, l; split2(acc, h, l);
            size_t o = ((size_t)(j >> 3) * 64 + b) * 8 + (j & 7);
            hc_h[o] = h; hc_l[o] = l;
        }
    }
}

// ---- big MFMA GEMM, A fp32 row-major (in-kernel split), B chunked hi/lo, prefetched ----
__global__ __launch_bounds__(256) void mfma_gemm_bigf(
    const float* __restrict__ Ap,
    const unsigned short* __restrict__ Bh, const unsigned short* __restrict__ Bl,
    const float* __restrict__ bias, float* __restrict__ C,
    int N, int Npad, int K, int Mtiles, int Ntiles, int inner_m) {
    __shared__ __align__(16) short lds[32768];   // 64 KB
    short* Ahs = lds;          // [8][128(m^kc)][8]
    short* Als = lds + 8192;
    short* Bhs = lds + 16384;  // [8][128][8]
    short* Bls = lds + 24576;
    int tid = threadIdx.x, lane = tid & 63, w = tid >> 6;
    int nwg = Mtiles * Ntiles;
    int orig = blockIdx.x;
    int q = nwg >> 3, r = nwg & 7;
    int xcd = orig & 7;
    int basew = (xcd < r) ? xcd * (q + 1) : r * (q + 1) + (xcd - r) * q;
    int wg = basew + (orig >> 3);
    int mt, nt;
    if (inner_m) { mt = wg % Mtiles; nt = wg / Mtiles; }
    else         { nt = wg % Ntiles; mt = wg / Ntiles; }
    int m0 = mt * 128, n0 = nt * 128;
    int wr = w >> 1, wc = w & 1;
    f32x4 acc[4][4];
    #pragma unroll
    for (int i = 0; i < 4; ++i)
        #pragma unroll
        for (int j = 0; j < 4; ++j) acc[i][j] = (f32x4){0.f, 0.f, 0.f, 0.f};
    int nsteps = K >> 6;
    float4 va[8];
    short8 rb[2][4];
    auto load_step = [&](int s) {
        int k0 = s * 64, kc0 = s * 8;
        #pragma unroll
        for (int it = 0; it < 8; ++it) {
            int idx = it * 256 + tid; int m = idx >> 4, k4 = idx & 15;
            va[it] = *(const float4*)(Ap + (size_t)(m0 + m) * K + k0 + k4 * 4);
        }
        #pragma unroll
        for (int it = 0; it < 4; ++it) {
            int g = w * 4 + it; int kcl = g >> 1; int rb0 = (g & 1) * 64;
            size_t gb = ((size_t)(kc0 + kcl) * Npad + n0 + rb0 + lane) * 8;
            rb[0][it] = *(const short8*)(Bh + gb);
            rb[1][it] = *(const short8*)(Bl + gb);
        }
    };
    load_step(0);
    for (int s = 0; s < nsteps; ++s) {
        __syncthreads();
        #pragma unroll
        for (int it = 0; it < 8; ++it) {
            int idx = it * 256 + tid; int m = idx >> 4, k4 = idx & 15;
            int kc = k4 >> 1, jh = (k4 & 1) * 4;
            float vv[4] = {va[it].x, va[it].y, va[it].z, va[it].w};
            short4v hv, lv;
            #pragma unroll
            for (int qq = 0; qq < 4; ++qq) {
                unsigned short h, l; split2(vv[qq], h, l);
                hv[qq] = (short)h; lv[qq] = (short)l;
            }
            int o = kc * 1024 + ((m ^ kc) << 3) + jh;
            *(short4v*)(Ahs + o) = hv;
            *(short4v*)(Als + o) = lv;
        }
        #pragma unroll
        for (int it = 0; it < 4; ++it) {
            int g = w * 4 + it; int kcl = g >> 1; int rb0 = (g & 1) * 64;
            int o = (kcl * 128 + rb0 + lane) * 8;
            *(short8*)(Bhs + o) = rb[0][it];
            *(short8*)(Bls + o) = rb[1][it];
        }
        __syncthreads();
        if (s + 1 < nsteps) load_step(s + 1);
        #pragma unroll
        for (int ks = 0; ks < 2; ++ks) {
            int kq = ks * 4 + (lane >> 4);
            short8 afh[4], afl[4], bfh[4], bfl[4];
            #pragma unroll
            for (int mi = 0; mi < 4; ++mi) {
                int row = wr * 64 + mi * 16 + (lane & 15);
                int o = kq * 1024 + ((row ^ kq) << 3);
                afh[mi] = *(const short8*)(Ahs + o);
                afl[mi] = *(const short8*)(Als + o);
            }
            #pragma unroll
            for (int ni = 0; ni < 4; ++ni) {
                int o = (kq * 128 + wc * 64 + ni * 16 + (lane & 15)) * 8;
                bfh[ni] = *(const short8*)(Bhs + o);
                bfl[ni] = *(const short8*)(Bls + o);
            }
            #pragma unroll
            for (int mi = 0; mi < 4; ++mi)
                #pragma unroll
                for (int ni = 0; ni < 4; ++ni) {
                    acc[mi][ni] = __builtin_amdgcn_mfma_f32_16x16x32_bf16(afh[mi], bfh[ni], acc[mi][ni], 0, 0, 0);
                    acc[mi][ni] = __builtin_amdgcn_mfma_f32_16x16x32_bf16(afh[mi], bfl[ni], acc[mi][ni], 0, 0, 0);
                    acc[mi][ni] = __builtin_amdgcn_mfma_f32_16x16x32_bf16(afl[mi], bfh[ni], acc[mi][ni], 0, 0, 0);
                }
        }
    }
    #pragma unroll
    for (int mi = 0; mi < 4; ++mi) {
        int rrow = m0 + wr * 64 + mi * 16 + ((lane >> 4) << 2);
        #pragma unroll
        for (int ni = 0; ni < 4; ++ni) {
            int c = n0 + wc * 64 + ni * 16 + (lane & 15);
            if (c < N) {
                float bv = bias ? bias[c] : 0.f;
                #pragma unroll
                for (int qq = 0; qq < 4; ++qq)
                    C[(size_t)(rrow + qq) * N + c] = acc[mi][ni][qq] + bv;
            }
        }
    }
}

// ---- small-M MFMA GEMM: M=64, tile 64x128, BK=64, K-split, prefetched ----
__global__ __launch_bounds__(256) void mfma_gemm_small(
    const unsigned short* __restrict__ A0h, const unsigned short* __restrict__ A0l,
    const unsigned short* __restrict__ B0h, const unsigned short* __restrict__ B0l,
    float* __restrict__ out, int Npad, int steps) {
    __shared__ __align__(16) short lds[24576];
    short* Ahs = lds;          // [8][64][8]
    short* Als = lds + 4096;
    short* Bhs = lds + 8192;   // [8][128][8]
    short* Bls = lds + 16384;
    int tid = threadIdx.x, lane = tid & 63, w = tid >> 6;
    int n0 = blockIdx.x * 128;
    int kc_base = blockIdx.y * steps * 8;
    out += (size_t)blockIdx.y * 64 * Npad;
    f32x4 acc[4][2];
    #pragma unroll
    for (int i = 0; i < 4; ++i)
        #pragma unroll
        for (int j = 0; j < 2; ++j) acc[i][j] = (f32x4){0.f, 0.f, 0.f, 0.f};
    short8 raa[2][2], rbb[2][4];
    auto load_step = [&](int s) {
        int kc0 = kc_base + s * 8;
        #pragma unroll
        for (int it = 0; it < 2; ++it) {
            int kcl = w * 2 + it; size_t off = ((size_t)(kc0 + kcl) * 64 + lane) * 8;
            raa[0][it] = *(const short8*)(A0h + off);
            raa[1][it] = *(const short8*)(A0l + off);
        }
        #pragma unroll
        for (int it = 0; it < 4; ++it) {
            int g = w * 4 + it; int kcl = g >> 1; int cb = (g & 1) * 64;
            size_t off = ((size_t)(kc0 + kcl) * Npad + n0 + cb + lane) * 8;
            rbb[0][it] = *(const short8*)(B0h + off);
            rbb[1][it] = *(const short8*)(B0l + off);
        }
    };
    load_step(0);
    for (int s = 0; s < steps; ++s) {
        __syncthreads();
        #pragma unroll
        for (int it = 0; it < 2; ++it) {
            int kcl = w * 2 + it; int o = (kcl * 64 + lane) * 8;
            *(short8*)(Ahs + o) = raa[0][it];
            *(short8*)(Als + o) = raa[1][it];
        }
        #pragma unroll
        for (int it = 0; it < 4; ++it) {
            int g = w * 4 + it; int kcl = g >> 1; int cb = (g & 1) * 64;
            int o = (kcl * 128 + cb + lane) * 8;
            *(short8*)(Bhs + o) = rbb[0][it];
            *(short8*)(Bls + o) = rbb[1][it];
        }
        __syncthreads();
        if (s + 1 < steps) load_step(s + 1);
        #pragma unroll
        for (int ks = 0; ks < 2; ++ks) {
            int kq = ks * 4 + (lane >> 4);
            short8 afh[4], afl[4], bfh[2], bfl[2];
            #pragma unroll
            for (int mi = 0; mi < 4; ++mi) {
                int o = (kq * 64 + mi * 16 + (lane & 15)) * 8;
                afh[mi] = *(const short8*)(Ahs + o);
                afl[mi] = *(const short8*)(Als + o);
            }
            #pragma unroll
            for (int ni = 0; ni < 2; ++ni) {
                int o = (kq * 128 + w * 32 + ni * 16 + (lane & 15)) * 8;
                bfh[ni] = *(const short8*)(Bhs + o);
                bfl[ni] = *(const short8*)(Bls + o);
            }
            #pragma unroll
            for (int mi = 0; mi < 4; ++mi)
                #pragma unroll
                for (int ni = 0; ni < 2; ++ni) {
                    acc[mi][ni] = __builtin_amdgcn_mfma_f32_16x16x32_bf16(afh[mi], bfh[ni], acc[mi][ni], 0, 0, 0);
                    acc[mi][ni] = __builtin_amdgcn_mfma_f32_16x16x32_bf16(afh[mi], bfl[ni], acc[mi][ni], 0, 0, 0);
                    acc[mi][ni] = __builtin_amdgcn_mfma_f32_16x16x32_bf16(afl[mi], bfh[ni], acc[mi][ni], 0, 0, 0);
                }
        }
    }
    #pragma unroll
    for (int mi = 0; mi < 4; ++mi) {
        int rrow = mi * 16 + ((lane >> 4) << 2);
        #pragma unroll
        for (int ni = 0; ni < 2; ++ni) {
            int c = n0 + w * 32 + ni * 16 + (lane & 15);
            #pragma unroll
            for (int qq = 0; qq < 4; ++qq)
                out[(size_t)(rrow + qq) * Npad + c] = acc[mi][ni][qq];
        }
    }
}

// ---- fused per-step attention: energy + softmax + alphas + context + gate -> x2 ----
// 64 blocks x 1024 threads; x2 written into axh[par] x2-part (chunked split)
__global__ __launch_bounds__(1024) void attn_ctx_kernel(
    const float* __restrict__ att_enc, const float* __restrict__ adg,
    const float* __restrict__ b_dec, const float* __restrict__ Wfull,
    const float* __restrict__ enc, const float* __restrict__ b_fbeta,
    float* __restrict__ alpha_out, unsigned short* __restrict__ x2h,
    unsigned short* __restrict__ x2l, int t) {
    int b = blockIdx.x; int tid = threadIdx.x;
    __shared__ float sdec[AD], sw[AD], sgate[AD], sal[256], sE[256], red[256];
    __shared__ float sctx[2][AD];
    if (tid < AD) {
        float s = b_dec[tid];
        #pragma unroll
        for (int ks = 0; ks < 8; ++ks) s += adg[((size_t)ks * BB + b) * 1024 + tid];
        sdec[tid] = s;
        sw[tid] = Wfull[tid];
    } else {
        int e = tid - AD;
        float s = b_fbeta[e];
        #pragma unroll
        for (int ks = 0; ks < 8; ++ks) s += adg[((size_t)ks * BB + b) * 1024 + AD + e];
        sgate[e] = s;
    }
    __syncthreads();
    // energy per patch: 16 waves
    int w = tid >> 6, lane = tid & 63;
    float4 sd0 = *(const float4*)&sdec[lane * 8];
    float4 sd1 = *(const float4*)&sdec[lane * 8 + 4];
    float4 sw0 = *(const float4*)&sw[lane * 8];
    float4 sw1 = *(const float4*)&sw[lane * 8 + 4];
    for (int p = w; p < PP; p += 16) {
        const float* row = att_enc + ((size_t)b * PP + p) * AD + lane * 8;
        float4 v0 = *(const float4*)row;
        float4 v1 = *(const float4*)(row + 4);
        float part = fmaxf(v0.x + sd0.x, 0.f) * sw0.x + fmaxf(v0.y + sd0.y, 0.f) * sw0.y +
                     fmaxf(v0.z + sd0.z, 0.f) * sw0.z + fmaxf(v0.w + sd0.w, 0.f) * sw0.w +
                     fmaxf(v1.x + sd1.x, 0.f) * sw1.x + fmaxf(v1.y + sd1.y, 0.f) * sw1.y +
                     fmaxf(v1.z + sd1.z, 0.f) * sw1.z + fmaxf(v1.w + sd1.w, 0.f) * sw1.w;
        #pragma unroll
        for (int off = 32; off > 0; off >>= 1) part += __shfl_down(part, off, 64);
        if (lane == 0) sE[p] = part;
    }
    __syncthreads();
    // softmax over 196 energies
    float myE = (tid < PP) ? sE[tid] : -1e30f;
    if (tid < 256) red[tid] = myE;
    __syncthreads();
    for (int s = 128; s > 0; s >>= 1) {
        if (tid < s) red[tid] = fmaxf(red[tid], red[tid + s]);
        __syncthreads();
    }
    float mx = red[0];
    __syncthreads();
    float ex = (tid < PP) ? __expf(myE - mx) : 0.f;
    if (tid < 256) red[tid] = ex;
    __syncthreads();
    for (int s = 128; s > 0; s >>= 1) {
        if (tid < s) red[tid] += red[tid + s];
        __syncthreads();
    }
    if (tid < PP) {
        float al = ex * (1.f / red[0]);
        sal[tid] = al;
        alpha_out[((size_t)b * TT + t) * PP + tid] = al;
    }
    __syncthreads();
    // context: 2-way patch split (98 patches per half)
    int e = tid & 511, half = tid >> 9;
    const float* basep = enc + (size_t)b * PP * ENCD + e;
    float s2 = 0.f;
    #pragma unroll 2
    for (int p = half * 98; p < half * 98 + 98; ++p) s2 += sal[p] * basep[(size_t)p * ENCD];
    sctx[half][e] = s2;
    __syncthreads();
    if (tid < AD) {
        float ctx = sctx[0][tid] + sctx[1][tid];
        float gate = sigf(sgate[tid]);
        unsigned short h, l; split2(gate * ctx, h, l);
        size_t o = ((size_t)(tid >> 3) * 64 + b) * 8 + (tid & 7);
        x2h[o] = h; x2l[o] = l;
    }
}

// ---- per-step: gates = [x2|h]@[Wih2;Whh](perm) + pregates -> LSTM, fused ----
// 256 blocks x 128 thr; block owns 64 b x 16 perm-cols (= 4 hidden units); K=1536
__global__ __launch_bounds__(128) void gates_lstm_kernel(
    const unsigned short* __restrict__ Ah, const unsigned short* __restrict__ Al,
    const unsigned short* __restrict__ Bh, const unsigned short* __restrict__ Bl,
    const float* __restrict__ pregates, float* __restrict__ c,
    unsigned short* __restrict__ ho_h, unsigned short* __restrict__ ho_l,
    float* __restrict__ h_all, int t) {
    __shared__ __align__(16) short lds[10240];  // A 2x8KB + B 2x2KB
    __shared__ float gl[64][17];
    short* Ahs = lds;           // [8][64][8]
    short* Als = lds + 4096;
    short* Bhs = lds + 8192;    // [8][16][8]
    short* Bls = lds + 9216;
    int tid = threadIdx.x, lane = tid & 63, w = tid >> 6;
    int n0 = blockIdx.x * 16;
    f32x4 acc[4];
    #pragma unroll
    for (int i = 0; i < 4; ++i) acc[i] = (f32x4){0.f, 0.f, 0.f, 0.f};
    short8 ra[2][4], rb[2];
    auto load_step = [&](int s) {
        int kc0 = s * 8;
        #pragma unroll
        for (int it = 0; it < 4; ++it) {
            int idx = it * 128 + tid; int kcl = idx >> 6, row = idx & 63;
            size_t off = ((size_t)(kc0 + kcl) * 64 + row) * 8;
            ra[0][it] = *(const short8*)(Ah + off);
            ra[1][it] = *(const short8*)(Al + off);
        }
        {
            int kcl = tid >> 4, col = tid & 15;
            size_t off = ((size_t)(kc0 + kcl) * 4096 + n0 + col) * 8;
            rb[0] = *(const short8*)(Bh + off);
            rb[1] = *(const short8*)(Bl + off);
        }
    };
    load_step(0);
    for (int s = 0; s < 24; ++s) {   // K = 24 * 64 = 1536
        __syncthreads();
        #pragma unroll
        for (int it = 0; it < 4; ++it) {
            int idx = it * 128 + tid; int kcl = idx >> 6, row = idx & 63;
            int o = (kcl * 64 + row) * 8;
            *(short8*)(Ahs + o) = ra[0][it];
            *(short8*)(Als + o) = ra[1][it];
        }
        {
            int kcl = tid >> 4, col = tid & 15;
            int o = (kcl * 16 + col) * 8;
            *(short8*)(Bhs + o) = rb[0];
            *(short8*)(Bls + o) = rb[1];
        }
        __syncthreads();
        if (s + 1 < 24) load_step(s + 1);
        // wave w covers kc-half w*4..w*4+3 (cross-wave k-split)
        int kq = w * 4 + (lane >> 4);
        short8 afh[4], afl[4], bfh, bfl;
        #pragma unroll
        for (int mi = 0; mi < 4; ++mi) {
            int o = (kq * 64 + mi * 16 + (lane & 15)) * 8;
            afh[mi] = *(const short8*)(Ahs + o);
            afl[mi] = *(const short8*)(Als + o);
        }
        int ob = (kq * 16 + (lane & 15)) * 8;
        bfh = *(const short8*)(Bhs + ob);
        bfl = *(const short8*)(Bls + ob);
        #pragma unroll
        for (int mi = 0; mi < 4; ++mi) {
            acc[mi] = __builtin_amdgcn_mfma_f32_16x16x32_bf16(afh[mi], bfh, acc[mi], 0, 0, 0);
            acc[mi] = __builtin_amdgcn_mfma_f32_16x16x32_bf16(afh[mi], bfl, acc[mi], 0, 0, 0);
            acc[mi] = __builtin_amdgcn_mfma_f32_16x16x32_bf16(afl[mi], bfh, acc[mi], 0, 0, 0);
        }
    }
    // cross-wave reduce + pregates add
    if (w == 0) {
        #pragma unroll
        for (int mi = 0; mi < 4; ++mi)
            #pragma unroll
            for (int qq = 0; qq < 4; ++qq)
                gl[mi * 16 + ((lane >> 4) << 2) + qq][lane & 15] = acc[mi][qq];
    }
    __syncthreads();
    if (w == 1) {
        #pragma unroll
        for (int mi = 0; mi < 4; ++mi)
            #pragma unroll
            for (int qq = 0; qq < 4; ++qq) {
                int r = mi * 16 + ((lane >> 4) << 2) + qq, cl = lane & 15;
                gl[r][cl] += acc[mi][qq] + pregates[((size_t)(t * 64 + r)) * 4096 + n0 + cl];
            }
    }
    __syncthreads();
    // LSTM pointwise: 64 b x 4 j per block
    #pragma unroll
    for (int i = 0; i < 2; ++i) {
        int idx = tid + i * 128;
        int bb = idx >> 2, jl = idx & 3;
        float iG = gl[bb][4 * jl + 0], fG = gl[bb][4 * jl + 1];
        float gG = gl[bb][4 * jl + 2], oG = gl[bb][4 * jl + 3];
        int j = (n0 >> 2) + jl;
        float cn = sigf(fG) * c[bb * HD + j] + sigf(iG) * tanhf(gG);
        c[bb * HD + j] = cn;
        float hn = sigf(oG) * tanhf(cn);
        unsigned short h, l; split2(hn, h, l);
        size_t o1 = ((size_t)(j >> 3) * 64 + bb) * 8 + (j & 7);
        ho_h[o1] = h; ho_l[o1] = l;
        h_all[((size_t)bb * TT + t) * HD + j] = hn;
    }
}

extern "C" void kernel_launch(void* const* d_in, const int* in_sizes, int n_in,
                              void* d_out, int out_size, void* d_ws, size_t ws_size,
                              hipStream_t stream) {
    const float* enc      = (const float*)d_in[0];
    const int*   captions = (const int*)d_in[1];
    const float* W_enc    = (const float*)d_in[3];
    const float* b_enc    = (const float*)d_in[4];
    const float* W_dec    = (const float*)d_in[5];
    const float* b_dec    = (const float*)d_in[6];
    const float* W_full   = (const float*)d_in[7];
    const float* table    = (const float*)d_in[9];
    const float* W_ih     = (const float*)d_in[10];   // [1536][4096]
    const float* b_ih     = (const float*)d_in[11];
    const float* W_hh     = (const float*)d_in[12];   // [1024][4096]
    const float* b_hh     = (const float*)d_in[13];
    const float* W_init_h = (const float*)d_in[14];
    const float* b_init_h = (const float*)d_in[15];
    const float* W_init_c = (const float*)d_in[16];
    const float* b_init_c = (const float*)d_in[17];
    const float* W_fbeta  = (const float*)d_in[18];
    const float* b_fbeta  = (const float*)d_in[19];
    const float* W_fc     = (const float*)d_in[20];
    const float* b_fc     = (const float*)d_in[21];

    float* preds  = (float*)d_out;                         // [64][24][20000]
    float* alphas = (float*)d_out + (size_t)BB * TT * VD;  // [64][24][196]

    // ---- workspace carve. Alias region (dead after loop) first; wfc overlays it. ----
    char* base = (char*)d_ws;
    size_t off = 0;
    auto take = [&](size_t b) { void* r = (void*)(base + off); off += (b + 255) & ~(size_t)255; return r; };
    float* att_enc = (float*)take((size_t)12544 * 512 * 4);                      // 25.7 MB
    unsigned short* wih1_h = (unsigned short*)take((size_t)128 * 4096 * 8 * 2);  // 8.4
    unsigned short* wih1_l = (unsigned short*)take((size_t)128 * 4096 * 8 * 2);
    unsigned short* wg2_h  = (unsigned short*)take((size_t)192 * 4096 * 8 * 2);  // 12.6
    unsigned short* wg2_l  = (unsigned short*)take((size_t)192 * 4096 * 8 * 2);
    unsigned short* watt_h = (unsigned short*)take((size_t)128 * 1024 * 8 * 2);  // 2.1
    unsigned short* watt_l = (unsigned short*)take((size_t)128 * 1024 * 8 * 2);
    unsigned short* wenc_h = (unsigned short*)take((size_t)64 * 512 * 8 * 2);    // 0.52
    unsigned short* wenc_l = (unsigned short*)take((size_t)64 * 512 * 8 * 2);
    float* pregates = (float*)take((size_t)TT * BB * 4096 * 4);                  // 25.2
    float* adg      = (float*)take((size_t)8 * BB * 1024 * 4);                   // 2.1
    float* emb_f    = (float*)take((size_t)TT * BB * ED * 4);                    // 6.3
    float* biasp    = (float*)take((size_t)4096 * 4);
    // alias end ~106 MB >= wfc's 82.3 MB; wfc written AFTER the loop
    unsigned short* wfc_h = (unsigned short*)(base);
    unsigned short* wfc_l = (unsigned short*)(base + (size_t)128 * VPAD * 8 * 2);
    // persistent (live across wfc write):
    float* c_buf = (float*)take((size_t)BB * HD * 4);
    float* mf    = (float*)take((size_t)BB * ENCD * 4);
    unsigned short* axh_h[2], *axh_l[2];   // [192 kc][64][8] : kc<64 = x2, kc>=64 = h
    axh_h[0] = (unsigned short*)take((size_t)192 * 64 * 8 * 2);
    axh_l[0] = (unsigned short*)take((size_t)192 * 64 * 8 * 2);
    axh_h[1] = (unsigned short*)take((size_t)192 * 64 * 8 * 2);
    axh_l[1] = (unsigned short*)take((size_t)192 * 64 * 8 * 2);
    float* h_all = (float*)take((size_t)TT * BB * HD * 4);                       // 6.3

    // ---- prologue ----
    split_w_kernel<<<dim3(2, 64), 256, 0, stream>>>(W_enc, wenc_h, wenc_l, 512, 512, 0, 512, 0, 0);
    split_w_kernel<<<dim3(2, 128), 256, 0, stream>>>(W_dec, watt_h, watt_l, 512, 1024, 0, 512, 0, 0);
    split_w_kernel<<<dim3(2, 128), 256, 0, stream>>>(W_fbeta, watt_h, watt_l, 512, 1024, 512, 512, 0, 0);
    split_w_kernel<<<dim3(16, 128), 256, 0, stream>>>(W_ih, wih1_h, wih1_l, 4096, 4096, 0, 4096, 0, 1);
    split_w_kernel<<<dim3(16, 64), 256, 0, stream>>>(W_ih, wg2_h, wg2_l, 4096, 4096, 0, 4096, 1024, 1);
    split_w_kernel<<<dim3(16, 128), 256, 0, stream>>>(W_hh, wg2_h + (size_t)64 * 4096 * 8,
                                                      wg2_l + (size_t)64 * 4096 * 8,
                                                      4096, 4096, 0, 4096, 0, 1);
    bias_perm_kernel<<<16, 256, 0, stream>>>(b_ih, b_hh, biasp);
    embed_f32_kernel<<<dim3(TT, BB), 256, 0, stream>>>(captions, table, emb_f);
    mean_kernel<<<BB, 512, 0, stream>>>(enc, mf);
    init_hc_kernel<<<dim3(BB, 2), 256, 0, stream>>>(mf, W_init_h, b_init_h, W_init_c, b_init_c,
                                                    axh_h[0] + HOFF, axh_l[0] + HOFF, c_buf);
    // att_enc = enc @ W_enc + b_enc : M=12544 N=512 K=512
    mfma_gemm_bigf<<<392, 256, 0, stream>>>(enc, wenc_h, wenc_l, b_enc, att_enc,
                                            512, 512, 512, 98, 4, 0);
    // pregates = emb @ W_ih[0:1024] (perm cols) + (b_ih+b_hh) perm : M=1536 N=4096 K=1024
    mfma_gemm_bigf<<<384, 256, 0, stream>>>(emb_f, wih1_h, wih1_l, biasp, pregates,
                                            4096, 4096, 1024, 12, 32, 1);

    for (int t = 0; t < TT; ++t) {
        int par = t & 1;
        // 1) adg = h @ [W_dec | W_fbeta] : M=64 N=1024 K=1024, Ksplit=8 (steps=2)
        mfma_gemm_small<<<dim3(8, 8), 256, 0, stream>>>(
            axh_h[par] + HOFF, axh_l[par] + HOFF, watt_h, watt_l, adg, 1024, 2);
        // 2) fused energy+softmax+alphas+context+gate -> x2 into axh[par]
        attn_ctx_kernel<<<BB, 1024, 0, stream>>>(att_enc, adg, b_dec, W_full, enc, b_fbeta,
                                                 alphas, axh_h[par], axh_l[par], t);
        // 3) gates = [x2|h]@[Wih2;Whh](perm) + pregates -> LSTM -> h into axh[1-par]
        gates_lstm_kernel<<<256, 128, 0, stream>>>(
            axh_h[par], axh_l[par], wg2_h, wg2_l, pregates, c_buf,
            axh_h[1 - par] + HOFF, axh_l[1 - par] + HOFF, h_all, t);
    }

    // step-phase buffers dead: split W_fc into the aliased region, then final GEMM
    split_w_kernel<<<dim3(79, 128), 256, 0, stream>>>(W_fc, wfc_h, wfc_l, VD, VPAD, 0, VPAD, 0, 0);
    mfma_gemm_bigf<<<1884, 256, 0, stream>>>(h_all, wfc_h, wfc_l, b_fc, preds,
                                             VD, VPAD, 1024, 12, 157, 1);
}

// Round 8
// 1532.150 us; speedup vs baseline: 1.0589x; 1.0589x over previous
//
#include <hip/hip_runtime.h>
#include <hip/hip_bf16.h>

// Problem dims (fixed)
#define BB 64      // batch
#define PP 196     // patches
#define ENCD 512   // encoder dim
#define ED 1024    // embed dim
#define HD 1024    // hidden
#define AD 512     // attention dim
#define VD 20000   // vocab
#define TT 24      // timesteps = lengths-1
#define VPAD 20096 // vocab padded to 128
#define HOFF 32768 // h-part offset (shorts) inside axh: 64 kc * 64 * 8

typedef __attribute__((ext_vector_type(8))) short short8;
typedef __attribute__((ext_vector_type(4))) short short4v;
typedef __attribute__((ext_vector_type(4))) float f32x4;

__device__ __forceinline__ float sigf(float x) { return 1.f / (1.f + __expf(-x)); }

// ---- fp32 -> bf16 split (hi + lo), RNE ----
__device__ __forceinline__ unsigned short f2bf(float f) {
    unsigned u = __builtin_bit_cast(unsigned, f);
    u = (u + 0x7FFFu + ((u >> 16) & 1u)) >> 16;
    return (unsigned short)u;
}
__device__ __forceinline__ void split2(float v, unsigned short& h, unsigned short& l) {
    h = f2bf(v);
    float hf = __builtin_bit_cast(float, ((unsigned)h) << 16);
    l = f2bf(v - hf);
}

// ---- weight split: fp32 [rows][N] -> chunked bf16 [K/8][Npad][8] hi/lo ----
// perm=1: output col n sources col (n&3)*1024 + (n>>2)  (gate-interleave)
__global__ __launch_bounds__(256) void split_w_kernel(
    const float* __restrict__ W, unsigned short* __restrict__ oh,
    unsigned short* __restrict__ ol, int N /*src pitch*/, int Npad, int coff,
    int Nlaunch, int rowoff, int perm) {
    int n = blockIdx.x * 256 + threadIdx.x;
    if (n >= Nlaunch) return;
    int kc = blockIdx.y;
    int src = perm ? ((n & 3) * 1024 + (n >> 2)) : n;
    short8 vh, vl;
    #pragma unroll
    for (int j = 0; j < 8; ++j) {
        float v = (src < N) ? W[(size_t)(rowoff + kc * 8 + j) * N + src] : 0.f;
        unsigned short h, l; split2(v, h, l);
        vh[j] = (short)h; vl[j] = (short)l;
    }
    size_t o = ((size_t)kc * Npad + coff + n) * 8;
    *(short8*)(oh + o) = vh; *(short8*)(ol + o) = vl;
}

// ---- embedding gather (fp32 rows, r = t*64+b) ----
__global__ __launch_bounds__(256) void embed_f32_kernel(
    const int* __restrict__ captions, const float* __restrict__ table,
    float* __restrict__ emb_f) {
    int t = blockIdx.x, b = blockIdx.y;
    int tok = captions[b * 25 + t];
    const float4* src = (const float4*)(table + (size_t)tok * ED);
    float4* dst = (float4*)(emb_f + ((size_t)t * BB + b) * ED);
    dst[threadIdx.x] = src[threadIdx.x];
}

// ---- permuted combined bias: out[n'] = b_ih[src]+b_hh[src] ----
__global__ __launch_bounds__(256) void bias_perm_kernel(
    const float* __restrict__ b_ih, const float* __restrict__ b_hh,
    float* __restrict__ out) {
    int n = blockIdx.x * 256 + threadIdx.x;
    int src = (n & 3) * 1024 + (n >> 2);
    out[n] = b_ih[src] + b_hh[src];
}

// ---- mean over patches ----
__global__ __launch_bounds__(512) void mean_kernel(const float* __restrict__ enc,
                                                   float* __restrict__ mf) {
    int b = blockIdx.x; int e = threadIdx.x;
    const float* base = enc + (size_t)b * PP * ENCD + e;
    float s = 0.f;
    #pragma unroll 4
    for (int p = 0; p < PP; ++p) s += base[(size_t)p * ENCD];
    mf[b * ENCD + e] = s * (1.f / PP);
}

// ---- h0/c0 init; h0 split written via hc pointers (pre-offset to axh h-part) ----
__global__ __launch_bounds__(256) void init_hc_kernel(
    const float* __restrict__ mf,
    const float* __restrict__ Wh, const float* __restrict__ bh,
    const float* __restrict__ Wc, const float* __restrict__ bc,
    unsigned short* __restrict__ hc_h, unsigned short* __restrict__ hc_l,
    float* __restrict__ c0) {
    int b = blockIdx.x;
    int isC = blockIdx.y;
    const float* W    = isC ? Wc : Wh;
    const float* bias = isC ? bc : bh;
    __shared__ float smf[ENCD];
    for (int i = threadIdx.x; i < ENCD; i += 256) smf[i] = mf[b * ENCD + i];
    __syncthreads();
    #pragma unroll
    for (int jj = 0; jj < 4; ++jj) {
        int j = threadIdx.x + jj * 256;
        float acc = bias[j];
        for (int k = 0; k < ENCD; ++k) acc += smf[k] * W[(size_t)k * HD + j];
        if (isC) c0[b * HD + j] = acc;
        else {
            unsigned short h, l; split2(acc, h, l);
            size_t o = ((size_t)(j >> 3) * 64 + b) * 8 + (j & 7);
            hc_h[o] = h; hc_l[o] = l;
        }
    }
}

// ---- big MFMA GEMM, A fp32 row-major (in-kernel split), B chunked hi/lo, prefetched ----
__global__ __launch_bounds__(256) void mfma_gemm_bigf(
    const float* __restrict__ Ap,
    const unsigned short* __restrict__ Bh, const unsigned short* __restrict__ Bl,
    const float* __restrict__ bias, float* __restrict__ C,
    int N, int Npad, int K, int Mtiles, int Ntiles, int inner_m) {
    __shared__ __align__(16) short lds[32768];   // 64 KB
    short* Ahs = lds;          // [8][128(m^kc)][8]
    short* Als = lds + 8192;
    short* Bhs = lds + 16384;  // [8][128][8]
    short* Bls = lds + 24576;
    int tid = threadIdx.x, lane = tid & 63, w = tid >> 6;
    int nwg = Mtiles * Ntiles;
    int orig = blockIdx.x;
    int q = nwg >> 3, r = nwg & 7;
    int xcd = orig & 7;
    int basew = (xcd < r) ? xcd * (q + 1) : r * (q + 1) + (xcd - r) * q;
    int wg = basew + (orig >> 3);
    int mt, nt;
    if (inner_m) { mt = wg % Mtiles; nt = wg / Mtiles; }
    else         { nt = wg % Ntiles; mt = wg / Ntiles; }
    int m0 = mt * 128, n0 = nt * 128;
    int wr = w >> 1, wc = w & 1;
    f32x4 acc[4][4];
    #pragma unroll
    for (int i = 0; i < 4; ++i)
        #pragma unroll
        for (int j = 0; j < 4; ++j) acc[i][j] = (f32x4){0.f, 0.f, 0.f, 0.f};
    int nsteps = K >> 6;
    float4 va[8];
    short8 rb[2][4];
    auto load_step = [&](int s) {
        int k0 = s * 64, kc0 = s * 8;
        #pragma unroll
        for (int it = 0; it < 8; ++it) {
            int idx = it * 256 + tid; int m = idx >> 4, k4 = idx & 15;
            va[it] = *(const float4*)(Ap + (size_t)(m0 + m) * K + k0 + k4 * 4);
        }
        #pragma unroll
        for (int it = 0; it < 4; ++it) {
            int g = w * 4 + it; int kcl = g >> 1; int rb0 = (g & 1) * 64;
            size_t gb = ((size_t)(kc0 + kcl) * Npad + n0 + rb0 + lane) * 8;
            rb[0][it] = *(const short8*)(Bh + gb);
            rb[1][it] = *(const short8*)(Bl + gb);
        }
    };
    load_step(0);
    for (int s = 0; s < nsteps; ++s) {
        __syncthreads();
        #pragma unroll
        for (int it = 0; it < 8; ++it) {
            int idx = it * 256 + tid; int m = idx >> 4, k4 = idx & 15;
            int kc = k4 >> 1, jh = (k4 & 1) * 4;
            float vv[4] = {va[it].x, va[it].y, va[it].z, va[it].w};
            short4v hv, lv;
            #pragma unroll
            for (int qq = 0; qq < 4; ++qq) {
                unsigned short h, l; split2(vv[qq], h, l);
                hv[qq] = (short)h; lv[qq] = (short)l;
            }
            int o = kc * 1024 + ((m ^ kc) << 3) + jh;
            *(short4v*)(Ahs + o) = hv;
            *(short4v*)(Als + o) = lv;
        }
        #pragma unroll
        for (int it = 0; it < 4; ++it) {
            int g = w * 4 + it; int kcl = g >> 1; int rb0 = (g & 1) * 64;
            int o = (kcl * 128 + rb0 + lane) * 8;
            *(short8*)(Bhs + o) = rb[0][it];
            *(short8*)(Bls + o) = rb[1][it];
        }
        __syncthreads();
        if (s + 1 < nsteps) load_step(s + 1);
        #pragma unroll
        for (int ks = 0; ks < 2; ++ks) {
            int kq = ks * 4 + (lane >> 4);
            short8 afh[4], afl[4], bfh[4], bfl[4];
            #pragma unroll
            for (int mi = 0; mi < 4; ++mi) {
                int row = wr * 64 + mi * 16 + (lane & 15);
                int o = kq * 1024 + ((row ^ kq) << 3);
                afh[mi] = *(const short8*)(Ahs + o);
                afl[mi] = *(const short8*)(Als + o);
            }
            #pragma unroll
            for (int ni = 0; ni < 4; ++ni) {
                int o = (kq * 128 + wc * 64 + ni * 16 + (lane & 15)) * 8;
                bfh[ni] = *(const short8*)(Bhs + o);
                bfl[ni] = *(const short8*)(Bls + o);
            }
            #pragma unroll
            for (int mi = 0; mi < 4; ++mi)
                #pragma unroll
                for (int ni = 0; ni < 4; ++ni) {
                    acc[mi][ni] = __builtin_amdgcn_mfma_f32_16x16x32_bf16(afh[mi], bfh[ni], acc[mi][ni], 0, 0, 0);
                    acc[mi][ni] = __builtin_amdgcn_mfma_f32_16x16x32_bf16(afh[mi], bfl[ni], acc[mi][ni], 0, 0, 0);
                    acc[mi][ni] = __builtin_amdgcn_mfma_f32_16x16x32_bf16(afl[mi], bfh[ni], acc[mi][ni], 0, 0, 0);
                }
        }
    }
    #pragma unroll
    for (int mi = 0; mi < 4; ++mi) {
        int rrow = m0 + wr * 64 + mi * 16 + ((lane >> 4) << 2);
        #pragma unroll
        for (int ni = 0; ni < 4; ++ni) {
            int c = n0 + wc * 64 + ni * 16 + (lane & 15);
            if (c < N) {
                float bv = bias ? bias[c] : 0.f;
                #pragma unroll
                for (int qq = 0; qq < 4; ++qq)
                    C[(size_t)(rrow + qq) * N + c] = acc[mi][ni][qq] + bv;
            }
        }
    }
}

// ---- phase-1: adg = h @ [W_dec|W_fbeta|Whh(perm)] — zero-barrier direct-fragment GEMM ----
// grid (40, 8): n-tile 128 x Ksplit 8 (16 kc each). 4 waves, wave owns 64x32 cols.
__global__ __launch_bounds__(256) void hgemm_direct(
    const unsigned short* __restrict__ Ah, const unsigned short* __restrict__ Al,
    const unsigned short* __restrict__ Bh, const unsigned short* __restrict__ Bl,
    float* __restrict__ out /*[8][64][5120]*/) {
    int tid = threadIdx.x, lane = tid & 63, w = tid >> 6;
    int n0 = blockIdx.x * 128 + w * 32;
    int kc0 = blockIdx.y * 16;
    out += (size_t)blockIdx.y * 64 * 5120;
    f32x4 acc[4][2];
    #pragma unroll
    for (int i = 0; i < 4; ++i)
        #pragma unroll
        for (int j = 0; j < 2; ++j) acc[i][j] = (f32x4){0.f, 0.f, 0.f, 0.f};
    #pragma unroll
    for (int s = 0; s < 4; ++s) {
        int kc = kc0 + s * 4 + (lane >> 4);
        short8 afh[4], afl[4], bfh[2], bfl[2];
        #pragma unroll
        for (int mi = 0; mi < 4; ++mi) {
            size_t o = ((size_t)kc * 64 + mi * 16 + (lane & 15)) * 8;
            afh[mi] = *(const short8*)(Ah + o);
            afl[mi] = *(const short8*)(Al + o);
        }
        #pragma unroll
        for (int ni = 0; ni < 2; ++ni) {
            size_t o = ((size_t)kc * 5120 + n0 + ni * 16 + (lane & 15)) * 8;
            bfh[ni] = *(const short8*)(Bh + o);
            bfl[ni] = *(const short8*)(Bl + o);
        }
        #pragma unroll
        for (int mi = 0; mi < 4; ++mi)
            #pragma unroll
            for (int ni = 0; ni < 2; ++ni) {
                acc[mi][ni] = __builtin_amdgcn_mfma_f32_16x16x32_bf16(afh[mi], bfh[ni], acc[mi][ni], 0, 0, 0);
                acc[mi][ni] = __builtin_amdgcn_mfma_f32_16x16x32_bf16(afh[mi], bfl[ni], acc[mi][ni], 0, 0, 0);
                acc[mi][ni] = __builtin_amdgcn_mfma_f32_16x16x32_bf16(afl[mi], bfh[ni], acc[mi][ni], 0, 0, 0);
            }
    }
    #pragma unroll
    for (int mi = 0; mi < 4; ++mi) {
        int rrow = mi * 16 + ((lane >> 4) << 2);
        #pragma unroll
        for (int ni = 0; ni < 2; ++ni) {
            int c = n0 + ni * 16 + (lane & 15);
            #pragma unroll
            for (int qq = 0; qq < 4; ++qq)
                out[(size_t)(rrow + qq) * 5120 + c] = acc[mi][ni][qq];
        }
    }
}

// ---- fused per-step attention: energy + softmax + alphas + context + gate -> x2 ----
// 64 blocks x 1024 threads; adg pitch 5120
__global__ __launch_bounds__(1024) void attn_ctx_kernel(
    const float* __restrict__ att_enc, const float* __restrict__ adg,
    const float* __restrict__ b_dec, const float* __restrict__ Wfull,
    const float* __restrict__ enc, const float* __restrict__ b_fbeta,
    float* __restrict__ alpha_out, unsigned short* __restrict__ x2h,
    unsigned short* __restrict__ x2l, int t) {
    int b = blockIdx.x; int tid = threadIdx.x;
    __shared__ float sdec[AD], sw[AD], sgate[AD], sal[256], sE[256], red[256];
    __shared__ float sctx[2][AD];
    if (tid < AD) {
        float s = b_dec[tid];
        #pragma unroll
        for (int ks = 0; ks < 8; ++ks) s += adg[((size_t)ks * BB + b) * 5120 + tid];
        sdec[tid] = s;
        sw[tid] = Wfull[tid];
    } else {
        int e = tid - AD;
        float s = b_fbeta[e];
        #pragma unroll
        for (int ks = 0; ks < 8; ++ks) s += adg[((size_t)ks * BB + b) * 5120 + 512 + e];
        sgate[e] = s;
    }
    __syncthreads();
    int w = tid >> 6, lane = tid & 63;
    float4 sd0 = *(const float4*)&sdec[lane * 8];
    float4 sd1 = *(const float4*)&sdec[lane * 8 + 4];
    float4 sw0 = *(const float4*)&sw[lane * 8];
    float4 sw1 = *(const float4*)&sw[lane * 8 + 4];
    for (int p = w; p < PP; p += 16) {
        const float* row = att_enc + ((size_t)b * PP + p) * AD + lane * 8;
        float4 v0 = *(const float4*)row;
        float4 v1 = *(const float4*)(row + 4);
        float part = fmaxf(v0.x + sd0.x, 0.f) * sw0.x + fmaxf(v0.y + sd0.y, 0.f) * sw0.y +
                     fmaxf(v0.z + sd0.z, 0.f) * sw0.z + fmaxf(v0.w + sd0.w, 0.f) * sw0.w +
                     fmaxf(v1.x + sd1.x, 0.f) * sw1.x + fmaxf(v1.y + sd1.y, 0.f) * sw1.y +
                     fmaxf(v1.z + sd1.z, 0.f) * sw1.z + fmaxf(v1.w + sd1.w, 0.f) * sw1.w;
        #pragma unroll
        for (int off = 32; off > 0; off >>= 1) part += __shfl_down(part, off, 64);
        if (lane == 0) sE[p] = part;
    }
    __syncthreads();
    float myE = (tid < PP) ? sE[tid] : -1e30f;
    if (tid < 256) red[tid] = myE;
    __syncthreads();
    for (int s = 128; s > 0; s >>= 1) {
        if (tid < s) red[tid] = fmaxf(red[tid], red[tid + s]);
        __syncthreads();
    }
    float mx = red[0];
    __syncthreads();
    float ex = (tid < PP) ? __expf(myE - mx) : 0.f;
    if (tid < 256) red[tid] = ex;
    __syncthreads();
    for (int s = 128; s > 0; s >>= 1) {
        if (tid < s) red[tid] += red[tid + s];
        __syncthreads();
    }
    if (tid < PP) {
        float al = ex * (1.f / red[0]);
        sal[tid] = al;
        alpha_out[((size_t)b * TT + t) * PP + tid] = al;
    }
    __syncthreads();
    int e = tid & 511, half = tid >> 9;
    const float* basep = enc + (size_t)b * PP * ENCD + e;
    float s2 = 0.f;
    #pragma unroll 2
    for (int p = half * 98; p < half * 98 + 98; ++p) s2 += sal[p] * basep[(size_t)p * ENCD];
    sctx[half][e] = s2;
    __syncthreads();
    if (tid < AD) {
        float ctx = sctx[0][tid] + sctx[1][tid];
        float gate = sigf(sgate[tid]);
        unsigned short h, l; split2(gate * ctx, h, l);
        size_t o = ((size_t)(tid >> 3) * 64 + b) * 8 + (tid & 7);
        x2h[o] = h; x2l[o] = l;
    }
}

// ---- phase-3: gates = x2 @ Wih2(perm) [K=512, cross-wave split] + pregates + hWhh
//      partials -> LSTM, fused. 128 blocks x 256 thr; block owns 64 b x 32 perm-cols. ----
__global__ __launch_bounds__(256) void gates_lstm2(
    const unsigned short* __restrict__ Ah, const unsigned short* __restrict__ Al,
    const unsigned short* __restrict__ Bh, const unsigned short* __restrict__ Bl,
    const float* __restrict__ pregates, const float* __restrict__ adg,
    float* __restrict__ c, unsigned short* __restrict__ ho_h,
    unsigned short* __restrict__ ho_l, float* __restrict__ h_all, int t) {
    __shared__ float gl[4][64][33];
    int tid = threadIdx.x, lane = tid & 63, w = tid >> 6;
    int n0 = blockIdx.x * 32;
    f32x4 acc[4][2];
    #pragma unroll
    for (int i = 0; i < 4; ++i)
        #pragma unroll
        for (int j = 0; j < 2; ++j) acc[i][j] = (f32x4){0.f, 0.f, 0.f, 0.f};
    #pragma unroll
    for (int s = 0; s < 4; ++s) {
        int kc = w * 16 + s * 4 + (lane >> 4);   // wave w owns K-quarter
        short8 afh[4], afl[4], bfh[2], bfl[2];
        #pragma unroll
        for (int mi = 0; mi < 4; ++mi) {
            size_t o = ((size_t)kc * 64 + mi * 16 + (lane & 15)) * 8;
            afh[mi] = *(const short8*)(Ah + o);
            afl[mi] = *(const short8*)(Al + o);
        }
        #pragma unroll
        for (int ni = 0; ni < 2; ++ni) {
            size_t o = ((size_t)kc * 4096 + n0 + ni * 16 + (lane & 15)) * 8;
            bfh[ni] = *(const short8*)(Bh + o);
            bfl[ni] = *(const short8*)(Bl + o);
        }
        #pragma unroll
        for (int mi = 0; mi < 4; ++mi)
            #pragma unroll
            for (int ni = 0; ni < 2; ++ni) {
                acc[mi][ni] = __builtin_amdgcn_mfma_f32_16x16x32_bf16(afh[mi], bfh[ni], acc[mi][ni], 0, 0, 0);
                acc[mi][ni] = __builtin_amdgcn_mfma_f32_16x16x32_bf16(afh[mi], bfl[ni], acc[mi][ni], 0, 0, 0);
                acc[mi][ni] = __builtin_amdgcn_mfma_f32_16x16x32_bf16(afl[mi], bfh[ni], acc[mi][ni], 0, 0, 0);
            }
    }
    // write wave partials (rows = batch)
    #pragma unroll
    for (int mi = 0; mi < 4; ++mi) {
        int rrow = mi * 16 + ((lane >> 4) << 2);
        #pragma unroll
        for (int ni = 0; ni < 2; ++ni) {
            int cl = ni * 16 + (lane & 15);
            #pragma unroll
            for (int qq = 0; qq < 4; ++qq)
                gl[w][rrow + qq][cl] = acc[mi][ni][qq];
        }
    }
    __syncthreads();
    // epilogue: 2 LSTM cells per thread (64 b x 8 j per block)
    #pragma unroll
    for (int i = 0; i < 2; ++i) {
        int idx = tid + i * 256;      // 0..511
        int b = idx >> 3, jl = idx & 7;
        float g4[4];
        #pragma unroll
        for (int qq = 0; qq < 4; ++qq)
            g4[qq] = gl[0][b][4 * jl + qq] + gl[1][b][4 * jl + qq] +
                     gl[2][b][4 * jl + qq] + gl[3][b][4 * jl + qq];
        {
            float4 pv = *(const float4*)&pregates[((size_t)(t * 64 + b)) * 4096 + n0 + 4 * jl];
            g4[0] += pv.x; g4[1] += pv.y; g4[2] += pv.z; g4[3] += pv.w;
        }
        #pragma unroll
        for (int ks = 0; ks < 8; ++ks) {
            float4 av = *(const float4*)&adg[((size_t)ks * BB + b) * 5120 + 1024 + n0 + 4 * jl];
            g4[0] += av.x; g4[1] += av.y; g4[2] += av.z; g4[3] += av.w;
        }
        int j = (n0 >> 2) + jl;
        float cn = sigf(g4[1]) * c[b * HD + j] + sigf(g4[0]) * tanhf(g4[2]);
        c[b * HD + j] = cn;
        float hn = sigf(g4[3]) * tanhf(cn);
        unsigned short h, l; split2(hn, h, l);
        size_t o1 = ((size_t)(j >> 3) * 64 + b) * 8 + (j & 7);
        ho_h[o1] = h; ho_l[o1] = l;
        h_all[((size_t)b * TT + t) * HD + j] = hn;
    }
}

extern "C" void kernel_launch(void* const* d_in, const int* in_sizes, int n_in,
                              void* d_out, int out_size, void* d_ws, size_t ws_size,
                              hipStream_t stream) {
    const float* enc      = (const float*)d_in[0];
    const int*   captions = (const int*)d_in[1];
    const float* W_enc    = (const float*)d_in[3];
    const float* b_enc    = (const float*)d_in[4];
    const float* W_dec    = (const float*)d_in[5];
    const float* b_dec    = (const float*)d_in[6];
    const float* W_full   = (const float*)d_in[7];
    const float* table    = (const float*)d_in[9];
    const float* W_ih     = (const float*)d_in[10];   // [1536][4096]
    const float* b_ih     = (const float*)d_in[11];
    const float* W_hh     = (const float*)d_in[12];   // [1024][4096]
    const float* b_hh     = (const float*)d_in[13];
    const float* W_init_h = (const float*)d_in[14];
    const float* b_init_h = (const float*)d_in[15];
    const float* W_init_c = (const float*)d_in[16];
    const float* b_init_c = (const float*)d_in[17];
    const float* W_fbeta  = (const float*)d_in[18];
    const float* b_fbeta  = (const float*)d_in[19];
    const float* W_fc     = (const float*)d_in[20];
    const float* b_fc     = (const float*)d_in[21];

    float* preds  = (float*)d_out;                         // [64][24][20000]
    float* alphas = (float*)d_out + (size_t)BB * TT * VD;  // [64][24][196]

    // ---- workspace carve. Alias region (dead after loop) first; wfc overlays it. ----
    char* base = (char*)d_ws;
    size_t off = 0;
    auto take = [&](size_t b) { void* r = (void*)(base + off); off += (b + 255) & ~(size_t)255; return r; };
    float* att_enc = (float*)take((size_t)12544 * 512 * 4);                      // 25.7 MB
    unsigned short* wbig_h = (unsigned short*)take((size_t)128 * 5120 * 8 * 2);  // 10.5
    unsigned short* wbig_l = (unsigned short*)take((size_t)128 * 5120 * 8 * 2);
    unsigned short* wih1_h = (unsigned short*)take((size_t)128 * 4096 * 8 * 2);  // 8.4
    unsigned short* wih1_l = (unsigned short*)take((size_t)128 * 4096 * 8 * 2);
    unsigned short* wih2_h = (unsigned short*)take((size_t)64 * 4096 * 8 * 2);   // 4.2
    unsigned short* wih2_l = (unsigned short*)take((size_t)64 * 4096 * 8 * 2);
    unsigned short* wenc_h = (unsigned short*)take((size_t)64 * 512 * 8 * 2);    // 0.52
    unsigned short* wenc_l = (unsigned short*)take((size_t)64 * 512 * 8 * 2);
    float* pregates = (float*)take((size_t)TT * BB * 4096 * 4);                  // 25.2
    float* adg      = (float*)take((size_t)8 * BB * 5120 * 4);                   // 10.5
    // emb_f shares adg's slot (emb_f dead before first adg write)
    float* emb_f    = adg;                                                        // 6.3 <= 10.5
    float* biasp    = (float*)take((size_t)4096 * 4);
    // alias end ~115 MB >= wfc's 82.3 MB; wfc written AFTER the loop
    unsigned short* wfc_h = (unsigned short*)(base);
    unsigned short* wfc_l = (unsigned short*)(base + (size_t)128 * VPAD * 8 * 2);
    // persistent (live across wfc write):
    float* c_buf = (float*)take((size_t)BB * HD * 4);
    float* mf    = (float*)take((size_t)BB * ENCD * 4);
    unsigned short* axh_h[2], *axh_l[2];   // [192 kc][64][8] : kc<64 = x2, kc>=64 = h
    axh_h[0] = (unsigned short*)take((size_t)192 * 64 * 8 * 2);
    axh_l[0] = (unsigned short*)take((size_t)192 * 64 * 8 * 2);
    axh_h[1] = (unsigned short*)take((size_t)192 * 64 * 8 * 2);
    axh_l[1] = (unsigned short*)take((size_t)192 * 64 * 8 * 2);
    float* h_all = (float*)take((size_t)TT * BB * HD * 4);                       // 6.3

    // ---- prologue ----
    split_w_kernel<<<dim3(2, 64), 256, 0, stream>>>(W_enc, wenc_h, wenc_l, 512, 512, 0, 512, 0, 0);
    split_w_kernel<<<dim3(2, 128), 256, 0, stream>>>(W_dec, wbig_h, wbig_l, 512, 5120, 0, 512, 0, 0);
    split_w_kernel<<<dim3(2, 128), 256, 0, stream>>>(W_fbeta, wbig_h, wbig_l, 512, 5120, 512, 512, 0, 0);
    split_w_kernel<<<dim3(16, 128), 256, 0, stream>>>(W_hh, wbig_h, wbig_l, 4096, 5120, 1024, 4096, 0, 1);
    split_w_kernel<<<dim3(16, 128), 256, 0, stream>>>(W_ih, wih1_h, wih1_l, 4096, 4096, 0, 4096, 0, 1);
    split_w_kernel<<<dim3(16, 64), 256, 0, stream>>>(W_ih, wih2_h, wih2_l, 4096, 4096, 0, 4096, 1024, 1);
    bias_perm_kernel<<<16, 256, 0, stream>>>(b_ih, b_hh, biasp);
    embed_f32_kernel<<<dim3(TT, BB), 256, 0, stream>>>(captions, table, emb_f);
    mean_kernel<<<BB, 512, 0, stream>>>(enc, mf);
    init_hc_kernel<<<dim3(BB, 2), 256, 0, stream>>>(mf, W_init_h, b_init_h, W_init_c, b_init_c,
                                                    axh_h[0] + HOFF, axh_l[0] + HOFF, c_buf);
    // att_enc = enc @ W_enc + b_enc : M=12544 N=512 K=512
    mfma_gemm_bigf<<<392, 256, 0, stream>>>(enc, wenc_h, wenc_l, b_enc, att_enc,
                                            512, 512, 512, 98, 4, 0);
    // pregates = emb @ W_ih[0:1024] (perm cols) + (b_ih+b_hh) perm : M=1536 N=4096 K=1024
    // NOTE: emb_f aliases adg — pregates GEMM reads emb_f before any adg write (loop starts after)
    mfma_gemm_bigf<<<384, 256, 0, stream>>>(emb_f, wih1_h, wih1_l, biasp, pregates,
                                            4096, 4096, 1024, 12, 32, 1);

    for (int t = 0; t < TT; ++t) {
        int par = t & 1;
        // 1) adg = h @ [W_dec | W_fbeta | Whh(perm)] : N=5120 K=1024, Ksplit=8, no barriers
        hgemm_direct<<<dim3(40, 8), 256, 0, stream>>>(
            axh_h[par] + HOFF, axh_l[par] + HOFF, wbig_h, wbig_l, adg);
        // 2) fused energy+softmax+alphas+context+gate -> x2 into axh[par]
        attn_ctx_kernel<<<BB, 1024, 0, stream>>>(att_enc, adg, b_dec, W_full, enc, b_fbeta,
                                                 alphas, axh_h[par], axh_l[par], t);
        // 3) gates = x2@Wih2 (K=512) + pregates + hWhh partials -> LSTM -> h into axh[1-par]
        gates_lstm2<<<128, 256, 0, stream>>>(
            axh_h[par], axh_l[par], wih2_h, wih2_l, pregates, adg, c_buf,
            axh_h[1 - par] + HOFF, axh_l[1 - par] + HOFF, h_all, t);
    }

    // step-phase buffers dead: split W_fc into the aliased region, then final GEMM
    split_w_kernel<<<dim3(79, 128), 256, 0, stream>>>(W_fc, wfc_h, wfc_l, VD, VPAD, 0, VPAD, 0, 0);
    mfma_gemm_bigf<<<1884, 256, 0, stream>>>(h_all, wfc_h, wfc_l, b_fc, preds,
                                             VD, VPAD, 1024, 12, 157, 1);
}